// Round 8
// baseline (426.534 us; speedup 1.0000x reference)
//
#include <hip/hip_runtime.h>

#define B_ 2
#define C_ 256
#define H_ 56
#define W_ 56
#define N_ 64
#define M_ 8
#define P_ 7
#define Y2_ (H_/2)               // 28 y-row pairs
#define Y4_ (H_/4)               // 14 y-row quads
#define SCTX_ 4                  // column chunks per ctx roi (box roi = whole)
#define JPN_ (1 + (M_)*SCTX_)    // 33 jobs per (b,n) -> 4224 blocks
#define WROW_ 8                  // padded weight-row stride (7 used + col7 = 0)

typedef _Float16 half2v __attribute__((ext_vector_type(2)));

#if __has_builtin(__builtin_amdgcn_fdot2)
#define FDOT2(a, b, c) __builtin_amdgcn_fdot2((a), (b), (c), false)
#else
static __device__ __forceinline__ float FDOT2(half2v a, half2v b, float c) {
    return fmaf((float)a.x, (float)b.x, fmaf((float)a.y, (float)b.y, c));
}
#endif

// ---- workspace layout (dword-element offsets) ----
// IDENTICAL footprint to the proven R0-R6 layout (~9.6 MB).  R7's crash was
// almost certainly the extra F_SCR region overflowing d_ws; the probes now
// reuse outS as scratch (they run BEFORE k_prep, which re-inits everything).
#define F_FMT4 0
#define N_FMT4 (B_*Y4_*W_*C_*2)              // 802,816 dw  f16 y-QUAD-packed fmap
#define F_OUTS (F_FMT4 + N_FMT4)
#define N_OUTS (B_*N_*49*C_)                 // 1,605,632 staging out [b][n][py][px][c]
#define WS_ELEMS (F_OUTS + N_OUTS)
#define WS_BYTES ((size_t)WS_ELEMS * 4)

// prep kernel block ranges (R2-proven: fused transpose + outS zeroing)
#define PREP_T (B_*Y4_*4*2)                  // 224: (b, y4, cgroup, xhalf) transpose
#define PREP_N (PREP_T + 784)                // + zero outS (784*2048 floats)

// ---------------------------------------------------------------------------
// k_prep (R2-verified): two jobs in one dispatch.
__global__ __launch_bounds__(256) void k_prep(const float* __restrict__ fm,
                                              float* __restrict__ ws_f) {
    __shared__ float t[28 * 257 + 8];        // [x28][y4][c64], x-stride 257 pad
    int bid = blockIdx.x;
    int tid = (int)threadIdx.x;

    if (bid < PREP_T) {                      // ---- y4 pack-transpose ----
        int xh = bid & 1;
        int cg = (bid >> 1) & 3;
        int y4 = (bid >> 3) % Y4_;
        int b  = (bid >> 3) / Y4_;
        int c0 = cg * 64, x0 = xh * 28;
        for (int e = tid; e < 64 * 4 * 28; e += 256) {
            int c_l = e / 112, rem = e % 112;
            int y_l = rem / 28, x_l = rem % 28;
            t[x_l * 257 + y_l * 64 + c_l] =
                fm[(((size_t)b * C_ + c0 + c_l) * H_ + 4 * y4 + y_l) * W_ + x0 + x_l];
        }
        __syncthreads();
        uint2* dst = (uint2*)ws_f;
        for (int e = tid; e < 28 * 64; e += 256) {
            int x_l = e >> 6, c_l = e & 63;
            const float* p = &t[x_l * 257 + c_l];
            half2v lo, hi; uint2 o;
            lo.x = (_Float16)p[0];   lo.y = (_Float16)p[64];
            hi.x = (_Float16)p[128]; hi.y = (_Float16)p[192];
            o.x = __builtin_bit_cast(unsigned int, lo);
            o.y = __builtin_bit_cast(unsigned int, hi);
            dst[(((size_t)b * Y4_ + y4) * W_ + x0 + x_l) * (size_t)C_ + c0 + c_l] = o;
        }
        return;
    }

    {                                        // ---- zero outS ----
        int tz = (bid - PREP_T) * 256 + tid; // < 200,704
        float4 z = {0.0f, 0.0f, 0.0f, 0.0f};
        float4* dst = (float4*)(ws_f + F_OUTS);
        dst[tz * 2]     = z;
        dst[tz * 2 + 1] = z;
    }
}

// ---------------------------------------------------------------------------
// Shared weight-gen + bounds prologue (exact R0/R4 math).  Returns false for
// empty chunks.  Used by k_main and both probes so the ablation holds the
// prologue constant.
static __device__ __forceinline__ bool prologue(int bid, int tid,
                                                const float* __restrict__ boxes,
                                                const float* __restrict__ gt,
                                                float (*s_wyf)[WROW_],
                                                unsigned int* s_wy2,
                                                float (*s_ax)[WROW_],
                                                int& b, int& n, int& xs, int& xe,
                                                int& ylo4, int& yhi4) {
    int j = bid % JPN_;
    n = (bid / JPN_) & (N_ - 1);
    b = bid / (JPN_ * N_);
    int k, s;
    if (j == 0) { k = 0; s = 0; }
    else        { k = 1 + ((j - 1) >> 2); s = (j - 1) & 3; }

    const float* bp = boxes + ((size_t)b * N_ + n) * 4;
    float bx1, by1, bx2, by2;
    if (k == 0) {
        bx1 = bp[0]; by1 = bp[1]; bx2 = bp[2]; by2 = bp[3];
    } else {
        const float* gp = gt + ((size_t)b * M_ + (k - 1)) * 4;
        bx1 = fminf(bp[0], gp[0]); by1 = fminf(bp[1], gp[1]);
        bx2 = fmaxf(bp[2], gp[2]); by2 = fmaxf(bp[3], gp[3]);
    }
    float rw = fmaxf(bx2 - bx1, 1.0f);
    float rh = fmaxf(by2 - by1, 1.0f);

    for (int e = tid; e < H_ * WROW_; e += 256) ((float*)s_wyf)[e] = 0.0f;
    for (int e = tid; e < W_ * WROW_; e += 256) ((float*)s_ax)[e] = 0.0f;
    __syncthreads();

    if (tid < P_) {                          // y samples, column-private
        int p = tid;
        float bin = rh / 7.0f;
        float gf  = ceilf(bin);
        int   g   = (int)gf;
        float ivg = 1.0f / gf;
        float start = by1 + (float)p * bin;
        for (int ss = 0; ss < g; ++ss) {
            float coord = start + ((float)ss + 0.5f) * bin * ivg;
            if (coord < -1.0f || coord > (float)H_) continue;
            float cc = fmaxf(coord, 0.0f);
            int low = (int)floorf(cc);
            int high; float l;
            if (low >= H_ - 1) { low = H_ - 1; high = H_ - 1; l = 0.0f; }
            else               { high = low + 1; l = cc - (float)low; }
            s_wyf[low][p]  += (1.0f - l) * ivg;
            s_wyf[high][p] += l * ivg;
        }
    } else if (tid >= 64 && tid < 64 + P_) { // x samples, column-private
        int p = tid - 64;
        float bin = rw / 7.0f;
        float gf  = ceilf(bin);
        int   g   = (int)gf;
        float ivg = 1.0f / gf;
        float fs  = (k == 0) ? ivg : ivg * (1.0f / (float)M_);
        float start = bx1 + (float)p * bin;
        for (int ss = 0; ss < g; ++ss) {
            float coord = start + ((float)ss + 0.5f) * bin * ivg;
            if (coord < -1.0f || coord > (float)W_) continue;
            float cc = fmaxf(coord, 0.0f);
            int low = (int)floorf(cc);
            int high; float l;
            if (low >= W_ - 1) { low = W_ - 1; high = W_ - 1; l = 0.0f; }
            else               { high = low + 1; l = cc - (float)low; }
            s_ax[low][p]  += (1.0f - l) * fs;
            s_ax[high][p] += l * fs;
        }
    }
    __syncthreads();

    if (tid < Y2_ * WROW_) {                 // pack y fp32 pairs -> half2
        int q2 = tid >> 3, col = tid & 7;
        half2v h;
        if (col < P_) { h.x = (_Float16)s_wyf[2 * q2][col]; h.y = (_Float16)s_wyf[2 * q2 + 1][col]; }
        else          { h.x = (_Float16)0.0f; h.y = (_Float16)0.0f; }
        s_wy2[tid] = __builtin_bit_cast(unsigned int, h);
    }
    __syncthreads();

    int xlo = min(max((int)floorf(fmaxf(bx1, 0.0f)), 0), W_ - 1);
    int xhi = min(max((int)floorf(bx1 + rw) + 1, 0), W_ - 1) + 1;
    int ylo = min(max((int)floorf(fmaxf(by1, 0.0f)), 0), H_ - 1);
    int yhi = min(max((int)floorf(by1 + rh) + 1, 0), H_ - 1) + 1;
    if (k == 0) { xs = xlo; xe = xhi; }
    else {
        int cw = (xhi - xlo + SCTX_ - 1) >> 2;
        xs = xlo + s * cw;
        xe = min(xs + cw, xhi);
    }
    ylo4 = ylo >> 2;
    yhi4 = (yhi + 3) >> 2;
    return xs < xe;
}

// ---------------------------------------------------------------------------
// ABLATION PROBES (R7 retry).  Scratch = the outS region itself (k_prep
// re-initializes it afterwards; probes run first).  All writes in-bounds of
// the PROVEN workspace footprint by construction.
//   MODE 1 "no-load":    prologue + full FDOT2/x-stage/atomic pattern, but
//                        d0..d3 synthesized per-iter (zero VMEM reads).
//   MODE 2 "no-compute": prologue + all 4 global loads per y4 (XOR-consumed),
//                        no FDOT2/x-stage; one plain store (index mod N_OUTS).
// Grids replicated (x3 / x2, bid % 4224) so probe durations rank top-5;
// per-probe base cost = shown_dur / replication.
template<int MODE>
__global__ __launch_bounds__(256, 4) void k_probe(const float* __restrict__ ws_f,
                                                  const float* __restrict__ boxes,
                                                  const float* __restrict__ gt,
                                                  float* __restrict__ scr) {
    __shared__ float        s_wyf[H_][WROW_];
    __shared__ unsigned int s_wy2[Y2_ * WROW_];
    __shared__ float        s_ax[W_][WROW_];

    int bid = (int)blockIdx.x % (B_ * N_ * JPN_);
    int tid = (int)threadIdx.x;
    int c   = tid;
    int b, n, xs, xe, ylo4, yhi4;
    if (!prologue(bid, tid, boxes, gt, s_wyf, s_wy2, s_ax, b, n, xs, xe, ylo4, yhi4))
        return;

    const uint2* f4 = (const uint2*)ws_f + (size_t)b * (Y4_ * W_ * C_);

    float acc[49];
#pragma unroll
    for (int q = 0; q < 49; ++q) acc[q] = 0.0f;
    int live = 0;
    unsigned int ix = 0;

    for (int x = xs; x < xe; x += 4) {
        float cs[4][P_];
#pragma unroll
        for (int i = 0; i < 4; ++i)
#pragma unroll
            for (int py = 0; py < P_; ++py) cs[i][py] = 0.0f;

        const uint2* cp = f4 + ((size_t)(ylo4 * W_ + x)) * C_ + c;
        for (int y4 = ylo4; y4 < yhi4; ++y4) {
            uint2 d0, d1, d2, d3;
            if (MODE == 1) {                 // synth: per-iter, not hoistable
                unsigned int u = (unsigned int)(y4 * 0x3C203C10 + x * 33) ^ (unsigned int)tid;
                d0.x = u;          d0.y = u ^ 0x00010001u;
                d1.x = u + 2;      d1.y = u ^ 0x00020002u;
                d2.x = u + 4;      d2.y = u ^ 0x00040004u;
                d3.x = u + 6;      d3.y = u ^ 0x00080008u;
            } else {                         // real loads (stale data: dead XOR)
                d0 = cp[0];
                d1 = cp[C_];
                d2 = cp[2 * C_];
                d3 = cp[3 * C_];
            }

            if (MODE == 1) {
                uint4 wa0 = *(const uint4*)&s_wy2[(2 * y4) * WROW_];
                uint4 wb0 = *(const uint4*)&s_wy2[(2 * y4) * WROW_ + 4];
                uint4 wa1 = *(const uint4*)&s_wy2[(2 * y4 + 1) * WROW_];
                uint4 wb1 = *(const uint4*)&s_wy2[(2 * y4 + 1) * WROW_ + 4];
                half2v w0[7], w1[7];
                w0[0] = __builtin_bit_cast(half2v, wa0.x);
                w0[1] = __builtin_bit_cast(half2v, wa0.y);
                w0[2] = __builtin_bit_cast(half2v, wa0.z);
                w0[3] = __builtin_bit_cast(half2v, wa0.w);
                w0[4] = __builtin_bit_cast(half2v, wb0.x);
                w0[5] = __builtin_bit_cast(half2v, wb0.y);
                w0[6] = __builtin_bit_cast(half2v, wb0.z);
                w1[0] = __builtin_bit_cast(half2v, wa1.x);
                w1[1] = __builtin_bit_cast(half2v, wa1.y);
                w1[2] = __builtin_bit_cast(half2v, wa1.z);
                w1[3] = __builtin_bit_cast(half2v, wa1.w);
                w1[4] = __builtin_bit_cast(half2v, wb1.x);
                w1[5] = __builtin_bit_cast(half2v, wb1.y);
                w1[6] = __builtin_bit_cast(half2v, wb1.z);
                half2v v0a = __builtin_bit_cast(half2v, d0.x);
                half2v v0b = __builtin_bit_cast(half2v, d0.y);
                half2v v1a = __builtin_bit_cast(half2v, d1.x);
                half2v v1b = __builtin_bit_cast(half2v, d1.y);
                half2v v2a = __builtin_bit_cast(half2v, d2.x);
                half2v v2b = __builtin_bit_cast(half2v, d2.y);
                half2v v3a = __builtin_bit_cast(half2v, d3.x);
                half2v v3b = __builtin_bit_cast(half2v, d3.y);
#pragma unroll
                for (int py = 0; py < P_; ++py) {
                    cs[0][py] = FDOT2(w1[py], v0b, FDOT2(w0[py], v0a, cs[0][py]));
                    cs[1][py] = FDOT2(w1[py], v1b, FDOT2(w0[py], v1a, cs[1][py]));
                    cs[2][py] = FDOT2(w1[py], v2b, FDOT2(w0[py], v2a, cs[2][py]));
                    cs[3][py] = FDOT2(w1[py], v3b, FDOT2(w0[py], v3a, cs[3][py]));
                }
            } else {                         // consume loads + LDS keepalive
                ix ^= d0.x ^ d0.y ^ d1.x ^ d1.y ^ d2.x ^ d2.y ^ d3.x ^ d3.y
                    ^ s_wy2[(2 * y4) * WROW_];
            }
            cp += W_ * C_;
        }

        if (MODE == 1) {
#pragma unroll
            for (int i = 0; i < 4; ++i) {
                if (x + i < xe) {
                    float av[8];
                    *(float4*)(&av[0]) = *(const float4*)&s_ax[x + i][0];
                    *(float4*)(&av[4]) = *(const float4*)&s_ax[x + i][4];
#pragma unroll
                    for (int px = 0; px < P_; ++px) {
                        float w = av[px];
                        if (w != 0.0f) {
                            live |= 1 << px;
#pragma unroll
                            for (int py = 0; py < P_; ++py)
                                acc[py * P_ + px] = fmaf(w, cs[i][py], acc[py * P_ + px]);
                        }
                    }
                }
            }
        }
    }

    if (MODE == 1) {                         // mirror real atomic epilogue
        float* os = scr + ((size_t)b * N_ + n) * (49 * C_) + c;   // in outS region
#pragma unroll
        for (int px = 0; px < P_; ++px) {
            if (live & (1 << px)) {
#pragma unroll
                for (int py = 0; py < P_; ++py)
                    atomicAdd(os + (py * P_ + px) * C_, acc[py * P_ + px]);
            }
        }
    } else {                                 // single plain store, in-bounds
        ix ^= __builtin_bit_cast(unsigned int, s_ax[xs][0]);
        size_t idx = ((size_t)blockIdx.x * 256 + tid) % (size_t)N_OUTS;
        scr[idx] = __builtin_bit_cast(float, ix);
    }
}

// ---------------------------------------------------------------------------
// k_main: R4 verbatim (best known, 79us).
__global__ __launch_bounds__(256, 4) void k_main(const float* __restrict__ ws_f,
                                                 const float* __restrict__ boxes,
                                                 const float* __restrict__ gt,
                                                 float* __restrict__ outs) {
    __shared__ float        s_wyf[H_][WROW_];
    __shared__ unsigned int s_wy2[Y2_ * WROW_];
    __shared__ float        s_ax[W_][WROW_];

    int bid = blockIdx.x;
    int tid = (int)threadIdx.x;
    int c   = tid;
    int b, n, xs, xe, ylo4, yhi4;
    if (!prologue(bid, tid, boxes, gt, s_wyf, s_wy2, s_ax, b, n, xs, xe, ylo4, yhi4))
        return;

    const uint2* f4 = (const uint2*)ws_f + (size_t)b * (Y4_ * W_ * C_);

    float acc[49];
#pragma unroll
    for (int q = 0; q < 49; ++q) acc[q] = 0.0f;
    int live = 0;

    for (int x = xs; x < xe; x += 4) {
        float cs[4][P_];
#pragma unroll
        for (int i = 0; i < 4; ++i)
#pragma unroll
            for (int py = 0; py < P_; ++py) cs[i][py] = 0.0f;

        const uint2* cp = f4 + ((size_t)(ylo4 * W_ + x)) * C_ + c;

        uint2 d0 = cp[0];
        uint2 d1 = cp[C_];
        uint2 d2 = cp[2 * C_];
        uint2 d3 = cp[3 * C_];
        for (int y4 = ylo4; y4 < yhi4; ++y4) {
            size_t nstep = (y4 + 1 < yhi4) ? (size_t)(W_ * C_) : 0;
            const uint2* cq = cp + nstep;
            uint2 e0 = cq[0];
            uint2 e1 = cq[C_];
            uint2 e2 = cq[2 * C_];
            uint2 e3 = cq[3 * C_];

            uint4 wa0 = *(const uint4*)&s_wy2[(2 * y4) * WROW_];
            uint4 wb0 = *(const uint4*)&s_wy2[(2 * y4) * WROW_ + 4];
            uint4 wa1 = *(const uint4*)&s_wy2[(2 * y4 + 1) * WROW_];
            uint4 wb1 = *(const uint4*)&s_wy2[(2 * y4 + 1) * WROW_ + 4];
            half2v w0[7], w1[7];
            w0[0] = __builtin_bit_cast(half2v, wa0.x);
            w0[1] = __builtin_bit_cast(half2v, wa0.y);
            w0[2] = __builtin_bit_cast(half2v, wa0.z);
            w0[3] = __builtin_bit_cast(half2v, wa0.w);
            w0[4] = __builtin_bit_cast(half2v, wb0.x);
            w0[5] = __builtin_bit_cast(half2v, wb0.y);
            w0[6] = __builtin_bit_cast(half2v, wb0.z);
            w1[0] = __builtin_bit_cast(half2v, wa1.x);
            w1[1] = __builtin_bit_cast(half2v, wa1.y);
            w1[2] = __builtin_bit_cast(half2v, wa1.z);
            w1[3] = __builtin_bit_cast(half2v, wa1.w);
            w1[4] = __builtin_bit_cast(half2v, wb1.x);
            w1[5] = __builtin_bit_cast(half2v, wb1.y);
            w1[6] = __builtin_bit_cast(half2v, wb1.z);
            half2v v0a = __builtin_bit_cast(half2v, d0.x);
            half2v v0b = __builtin_bit_cast(half2v, d0.y);
            half2v v1a = __builtin_bit_cast(half2v, d1.x);
            half2v v1b = __builtin_bit_cast(half2v, d1.y);
            half2v v2a = __builtin_bit_cast(half2v, d2.x);
            half2v v2b = __builtin_bit_cast(half2v, d2.y);
            half2v v3a = __builtin_bit_cast(half2v, d3.x);
            half2v v3b = __builtin_bit_cast(half2v, d3.y);
#pragma unroll
            for (int py = 0; py < P_; ++py) {
                cs[0][py] = FDOT2(w1[py], v0b, FDOT2(w0[py], v0a, cs[0][py]));
                cs[1][py] = FDOT2(w1[py], v1b, FDOT2(w0[py], v1a, cs[1][py]));
                cs[2][py] = FDOT2(w1[py], v2b, FDOT2(w0[py], v2a, cs[2][py]));
                cs[3][py] = FDOT2(w1[py], v3b, FDOT2(w0[py], v3a, cs[3][py]));
            }
            d0 = e0; d1 = e1; d2 = e2; d3 = e3;
            cp = cq;
        }

#pragma unroll
        for (int i = 0; i < 4; ++i) {
            if (x + i < xe) {
                float av[8];
                *(float4*)(&av[0]) = *(const float4*)&s_ax[x + i][0];
                *(float4*)(&av[4]) = *(const float4*)&s_ax[x + i][4];
#pragma unroll
                for (int px = 0; px < P_; ++px) {
                    float w = av[px];
                    if (w != 0.0f) {
                        live |= 1 << px;
#pragma unroll
                        for (int py = 0; py < P_; ++py)
                            acc[py * P_ + px] = fmaf(w, cs[i][py], acc[py * P_ + px]);
                    }
                }
            }
        }
    }

    float* os = outs + ((size_t)b * N_ + n) * (49 * C_) + c;
#pragma unroll
    for (int px = 0; px < P_; ++px) {
        if (live & (1 << px)) {
#pragma unroll
            for (int py = 0; py < P_; ++py)
                atomicAdd(os + (py * P_ + px) * C_, acc[py * P_ + px]);
        }
    }
}

// ---------------------------------------------------------------------------
// k_final (R1-verified): outS -> out transpose, 512 blocks.
__global__ __launch_bounds__(256) void k_final(const float* __restrict__ outs,
                                               float* __restrict__ out) {
    __shared__ float t[49 * 65];
    int bid = blockIdx.x;
    int cg  = bid & 3;
    int bn  = bid >> 2;
    int tid = (int)threadIdx.x;
    const float* src = outs + (size_t)bn * (49 * C_) + cg * 64;
    for (int e = tid; e < 49 * 64; e += 256) {
        int q = e >> 6, c = e & 63;
        t[q * 65 + c] = src[q * C_ + c];
    }
    __syncthreads();
    float* dst = out + (size_t)bn * (C_ * 49) + (size_t)cg * 64 * 49;
    for (int e = tid; e < 64 * 49; e += 256) {
        int c = e / 49, q = e - c * 49;
        dst[e] = t[q * 65 + c];
    }
}

// ---------------------------------------------------------------------------
extern "C" void kernel_launch(void* const* d_in, const int* in_sizes, int n_in,
                              void* d_out, int out_size, void* d_ws, size_t ws_size,
                              hipStream_t stream) {
    const float* fm    = (const float*)d_in[0];
    const float* boxes = (const float*)d_in[1];
    const float* gt    = (const float*)d_in[2];
    float* ws_f = (float*)d_ws;
    float* out  = (float*)d_out;
    float* outs = ws_f + F_OUTS;

    // ---- ablation probes: scratch = outS region (re-inited by k_prep after).
    // Gated on ws_size so they can never write past the provided workspace.
    if (ws_size >= WS_BYTES) {
        k_probe<1><<<3 * B_ * N_ * JPN_, 256, 0, stream>>>(ws_f, boxes, gt, outs);
        k_probe<2><<<2 * B_ * N_ * JPN_, 256, 0, stream>>>(ws_f, boxes, gt, outs);
    }

    // ---- real pipeline (R4 verbatim) ----
    k_prep<<<PREP_N, 256, 0, stream>>>(fm, ws_f);
    k_main<<<B_ * N_ * JPN_, 256, 0, stream>>>(ws_f, boxes, gt, outs);
    k_final<<<B_ * N_ * 4, 256, 0, stream>>>(outs, out);
}

// Round 9
// 142.161 us; speedup vs baseline: 3.0004x; 3.0004x over previous
//
#include <hip/hip_runtime.h>

#define B_ 2
#define C_ 256
#define H_ 56
#define W_ 56
#define N_ 64
#define M_ 8
#define P_ 7
#define Y2_ (H_/2)               // 28 y-row pairs
#define Y4_ (H_/4)               // 14 y-row quads
#define SCTX_ 4                  // column chunks per ctx roi (box roi = whole)
#define JPN_ (1 + (M_)*SCTX_)    // 33 jobs per (b,n) -> 4224 blocks (fallback)
#define JP2_ (9*4)               // 36 px-pair jobs per (b,n) -> 4608 (path P)
#define WROW_ 8                  // padded weight-row stride (7 used + col7 = 0)

typedef _Float16 half2v __attribute__((ext_vector_type(2)));

#if __has_builtin(__builtin_amdgcn_fdot2)
#define FDOT2(a, b, c) __builtin_amdgcn_fdot2((a), (b), (c), false)
#else
static __device__ __forceinline__ float FDOT2(half2v a, half2v b, float c) {
    return fmaf((float)a.x, (float)b.x, fmaf((float)a.y, (float)b.y, c));
}
#endif

// ---- workspace layout (dword-element offsets) ----
#define F_FMT4 0
#define N_FMT4 (B_*Y4_*W_*C_*2)              // 802,816 dw  f16 y-QUAD-packed fmap
#define F_OUTS (F_FMT4 + N_FMT4)             // fallback: atomic staging
#define N_OUTS (B_*N_*49*C_)                 // 1,605,632 dw
#define WS_BYTES_F ((size_t)(F_OUTS + N_OUTS) * 4)       // 9.6 MB (proven)
// path P: plain-store partials.  part[bn][px][k 0..8][py][c]
#define F_PART (F_FMT4 + N_FMT4)
#define N_PART (B_*N_*7*9*7*C_)              // 14,450,688 dw = 57.8 MB
#define WS_BYTES_P ((size_t)(F_PART + N_PART) * 4)       // ~61.0 MB (gated)

// prep kernel block ranges
#define PREP_T (B_*Y4_*4*2)                  // 224: transpose
#define PREP_N (PREP_T + 784)                // fallback: + zero outS

// ---------------------------------------------------------------------------
// k_prep (R2-verified).  Path P launches only the first PREP_T blocks.
__global__ __launch_bounds__(256) void k_prep(const float* __restrict__ fm,
                                              float* __restrict__ ws_f) {
    __shared__ float t[28 * 257 + 8];        // [x28][y4][c64], x-stride 257 pad
    int bid = blockIdx.x;
    int tid = (int)threadIdx.x;

    if (bid < PREP_T) {                      // ---- y4 pack-transpose ----
        int xh = bid & 1;
        int cg = (bid >> 1) & 3;
        int y4 = (bid >> 3) % Y4_;
        int b  = (bid >> 3) / Y4_;
        int c0 = cg * 64, x0 = xh * 28;
        for (int e = tid; e < 64 * 4 * 28; e += 256) {
            int c_l = e / 112, rem = e % 112;
            int y_l = rem / 28, x_l = rem % 28;
            t[x_l * 257 + y_l * 64 + c_l] =
                fm[(((size_t)b * C_ + c0 + c_l) * H_ + 4 * y4 + y_l) * W_ + x0 + x_l];
        }
        __syncthreads();
        uint2* dst = (uint2*)ws_f;
        for (int e = tid; e < 28 * 64; e += 256) {
            int x_l = e >> 6, c_l = e & 63;
            const float* p = &t[x_l * 257 + c_l];
            half2v lo, hi; uint2 o;
            lo.x = (_Float16)p[0];   lo.y = (_Float16)p[64];
            hi.x = (_Float16)p[128]; hi.y = (_Float16)p[192];
            o.x = __builtin_bit_cast(unsigned int, lo);
            o.y = __builtin_bit_cast(unsigned int, hi);
            dst[(((size_t)b * Y4_ + y4) * W_ + x0 + x_l) * (size_t)C_ + c0 + c_l] = o;
        }
        return;
    }

    {                                        // ---- zero outS (fallback only) ----
        int tz = (bid - PREP_T) * 256 + tid; // < 200,704
        float4 z = {0.0f, 0.0f, 0.0f, 0.0f};
        float4* dst = (float4*)(ws_f + F_OUTS);
        dst[tz * 2]     = z;
        dst[tz * 2 + 1] = z;
    }
}

// ---------------------------------------------------------------------------
// Shared weight-gen (R0-proven serial column-private form).  Fills s_wyf,
// s_wy2, s_ax for roi (k: 0=box, 1..8=ctx union).  Returns roi coords.
static __device__ __forceinline__ void gen_weights(int k, int b, int n, int tid,
                                                   const float* __restrict__ boxes,
                                                   const float* __restrict__ gt,
                                                   float (*s_wyf)[WROW_],
                                                   unsigned int* s_wy2,
                                                   float (*s_ax)[WROW_],
                                                   float& bx1, float& by1,
                                                   float& rw, float& rh) {
    const float* bp = boxes + ((size_t)b * N_ + n) * 4;
    float bx2, by2;
    if (k == 0) {
        bx1 = bp[0]; by1 = bp[1]; bx2 = bp[2]; by2 = bp[3];
    } else {
        const float* gp = gt + ((size_t)b * M_ + (k - 1)) * 4;
        bx1 = fminf(bp[0], gp[0]); by1 = fminf(bp[1], gp[1]);
        bx2 = fmaxf(bp[2], gp[2]); by2 = fmaxf(bp[3], gp[3]);
    }
    rw = fmaxf(bx2 - bx1, 1.0f);
    rh = fmaxf(by2 - by1, 1.0f);

    for (int e = tid; e < H_ * WROW_; e += 256) ((float*)s_wyf)[e] = 0.0f;
    for (int e = tid; e < W_ * WROW_; e += 256) ((float*)s_ax)[e] = 0.0f;
    __syncthreads();

    if (tid < P_) {                          // y samples, column-private
        int p = tid;
        float bin = rh / 7.0f;
        float gf  = ceilf(bin);
        int   g   = (int)gf;
        float ivg = 1.0f / gf;
        float start = by1 + (float)p * bin;
        for (int ss = 0; ss < g; ++ss) {
            float coord = start + ((float)ss + 0.5f) * bin * ivg;
            if (coord < -1.0f || coord > (float)H_) continue;
            float cc = fmaxf(coord, 0.0f);
            int low = (int)floorf(cc);
            int high; float l;
            if (low >= H_ - 1) { low = H_ - 1; high = H_ - 1; l = 0.0f; }
            else               { high = low + 1; l = cc - (float)low; }
            s_wyf[low][p]  += (1.0f - l) * ivg;
            s_wyf[high][p] += l * ivg;
        }
    } else if (tid >= 64 && tid < 64 + P_) { // x samples, column-private
        int p = tid - 64;
        float bin = rw / 7.0f;
        float gf  = ceilf(bin);
        int   g   = (int)gf;
        float ivg = 1.0f / gf;
        float fs  = (k == 0) ? ivg : ivg * (1.0f / (float)M_);
        float start = bx1 + (float)p * bin;
        for (int ss = 0; ss < g; ++ss) {
            float coord = start + ((float)ss + 0.5f) * bin * ivg;
            if (coord < -1.0f || coord > (float)W_) continue;
            float cc = fmaxf(coord, 0.0f);
            int low = (int)floorf(cc);
            int high; float l;
            if (low >= W_ - 1) { low = W_ - 1; high = W_ - 1; l = 0.0f; }
            else               { high = low + 1; l = cc - (float)low; }
            s_ax[low][p]  += (1.0f - l) * fs;
            s_ax[high][p] += l * fs;
        }
    }
    __syncthreads();

    if (tid < Y2_ * WROW_) {                 // pack y fp32 pairs -> half2
        int q2 = tid >> 3, col = tid & 7;
        half2v h;
        if (col < P_) { h.x = (_Float16)s_wyf[2 * q2][col]; h.y = (_Float16)s_wyf[2 * q2 + 1][col]; }
        else          { h.x = (_Float16)0.0f; h.y = (_Float16)0.0f; }
        s_wy2[tid] = __builtin_bit_cast(unsigned int, h);
    }
    __syncthreads();
}

// ---------------------------------------------------------------------------
// k_mainP (path P): px-pair jobs, PLAIN STORES — no atomics.  R8's ablation
// proved k_main is atomic-bound (no-load probe = 74us = whole kernel; atomic
// rate pinned at ~265 G adds/s in both probe and k_main).  Each job (b,n,
// roi k, pair s) owns px {2s,2s+1} (R6-verified support math) and writes its
// partial to a private slot part[bn][px][k][py][c] — 9 static writers per
// output, conflict-free, coalesced.  Inner loop keeps R0's 4-col x 4-row
// burst (MLP=4; R6 proved collapsing it to 1 costs 50%).
__global__ __launch_bounds__(256, 4) void k_mainP(const float* __restrict__ ws_f,
                                                  const float* __restrict__ boxes,
                                                  const float* __restrict__ gt,
                                                  float* __restrict__ part) {
    __shared__ float        s_wyf[H_][WROW_];
    __shared__ unsigned int s_wy2[Y2_ * WROW_];
    __shared__ float        s_ax[W_][WROW_];

    int bid = blockIdx.x;
    int j   = bid % JP2_;                    // 0..35
    int n   = (bid / JP2_) & (N_ - 1);
    int b   = bid / (JP2_ * N_);
    int k   = j >> 2;                        // 0 = box, 1..8 = ctx union
    int s   = j & 3;
    int p0  = 2 * s;                         // px pair {p0, p0+1} (s==3: p0 only)
    int tid = (int)threadIdx.x;
    int c   = tid;

    float bx1, by1, rw, rh;
    gen_weights(k, b, n, tid, boxes, gt, s_wyf, s_wy2, s_ax, bx1, by1, rw, rh);

    // ---- px-pair column support (R6-verified formulas) ----
    float binw = rw * (1.0f / 7.0f);
    float lo_f = bx1 + (float)p0 * binw;
    int   pe   = (p0 + 1 < P_) ? p0 + 2 : p0 + 1;
    float hi_f = bx1 + (float)pe * binw;
    int xs = min(max((int)floorf(fmaxf(lo_f, 0.0f)), 0), W_ - 1);
    int xe = min(max((int)floorf(fminf(hi_f, (float)W_)) + 1, 0), W_ - 1) + 1;

    int ylo = min(max((int)floorf(fmaxf(by1, 0.0f)), 0), H_ - 1);
    int yhi = min(max((int)floorf(by1 + rh) + 1, 0), H_ - 1) + 1;
    int ylo4 = ylo >> 2;
    int yhi4 = (yhi + 3) >> 2;

    const uint2* f4 = (const uint2*)ws_f + (size_t)b * (Y4_ * W_ * C_);

    float acc0[P_], acc1[P_];
#pragma unroll
    for (int q = 0; q < P_; ++q) { acc0[q] = 0.0f; acc1[q] = 0.0f; }

    if (xs < xe) {                           // empty support -> store zeros
        for (int x = xs; x < xe; x += 4) {
            float cs[4][P_];
#pragma unroll
            for (int i = 0; i < 4; ++i)
#pragma unroll
                for (int py = 0; py < P_; ++py) cs[i][py] = 0.0f;

            // x+1..x+3 over-reads stay inside d_ws (fmt4 tail / part region);
            // garbage never enters acc (x-stage gated on xe).
            const uint2* cp = f4 + ((size_t)(ylo4 * W_ + x)) * C_ + c;
            for (int y4 = ylo4; y4 < yhi4; ++y4) {
                uint2 d0 = cp[0];
                uint2 d1 = cp[C_];
                uint2 d2 = cp[2 * C_];
                uint2 d3 = cp[3 * C_];
                uint4 wa0 = *(const uint4*)&s_wy2[(2 * y4) * WROW_];
                uint4 wb0 = *(const uint4*)&s_wy2[(2 * y4) * WROW_ + 4];
                uint4 wa1 = *(const uint4*)&s_wy2[(2 * y4 + 1) * WROW_];
                uint4 wb1 = *(const uint4*)&s_wy2[(2 * y4 + 1) * WROW_ + 4];
                half2v w0[7], w1[7];
                w0[0] = __builtin_bit_cast(half2v, wa0.x);
                w0[1] = __builtin_bit_cast(half2v, wa0.y);
                w0[2] = __builtin_bit_cast(half2v, wa0.z);
                w0[3] = __builtin_bit_cast(half2v, wa0.w);
                w0[4] = __builtin_bit_cast(half2v, wb0.x);
                w0[5] = __builtin_bit_cast(half2v, wb0.y);
                w0[6] = __builtin_bit_cast(half2v, wb0.z);
                w1[0] = __builtin_bit_cast(half2v, wa1.x);
                w1[1] = __builtin_bit_cast(half2v, wa1.y);
                w1[2] = __builtin_bit_cast(half2v, wa1.z);
                w1[3] = __builtin_bit_cast(half2v, wa1.w);
                w1[4] = __builtin_bit_cast(half2v, wb1.x);
                w1[5] = __builtin_bit_cast(half2v, wb1.y);
                w1[6] = __builtin_bit_cast(half2v, wb1.z);
                half2v v0a = __builtin_bit_cast(half2v, d0.x);
                half2v v0b = __builtin_bit_cast(half2v, d0.y);
                half2v v1a = __builtin_bit_cast(half2v, d1.x);
                half2v v1b = __builtin_bit_cast(half2v, d1.y);
                half2v v2a = __builtin_bit_cast(half2v, d2.x);
                half2v v2b = __builtin_bit_cast(half2v, d2.y);
                half2v v3a = __builtin_bit_cast(half2v, d3.x);
                half2v v3b = __builtin_bit_cast(half2v, d3.y);
#pragma unroll
                for (int py = 0; py < P_; ++py) {
                    cs[0][py] = FDOT2(w1[py], v0b, FDOT2(w0[py], v0a, cs[0][py]));
                    cs[1][py] = FDOT2(w1[py], v1b, FDOT2(w0[py], v1a, cs[1][py]));
                    cs[2][py] = FDOT2(w1[py], v2b, FDOT2(w0[py], v2a, cs[2][py]));
                    cs[3][py] = FDOT2(w1[py], v3b, FDOT2(w0[py], v3a, cs[3][py]));
                }
                cp += W_ * C_;
            }

            // ---- x-stage: only the owned px pair (p0 even -> 8B aligned;
            //      p0==6 reads pad col 7 == 0 -> acc1 stays 0) ----
#pragma unroll
            for (int i = 0; i < 4; ++i) {
                if (x + i < xe) {                     // wave-uniform
                    float2 axv = *(const float2*)&s_ax[x + i][p0];
#pragma unroll
                    for (int py = 0; py < P_; ++py) {
                        acc0[py] = fmaf(axv.x, cs[i][py], acc0[py]);
                        acc1[py] = fmaf(axv.y, cs[i][py], acc1[py]);
                    }
                }
            }
        }
    }

    // ---- epilogue: PLAIN coalesced stores to private slots ----
    size_t bn = (size_t)b * N_ + n;
    float* pp = part + (((bn * 7 + p0) * 9 + k) * 7) * 256 + c;
#pragma unroll
    for (int py = 0; py < P_; ++py) pp[py * 256] = acc0[py];
    if (p0 + 1 < P_) {
        float* pq = part + (((bn * 7 + p0 + 1) * 9 + k) * 7) * 256 + c;
#pragma unroll
        for (int py = 0; py < P_; ++py) pq[py * 256] = acc1[py];
    }
}

// ---------------------------------------------------------------------------
// k_reduce (path P): out[bn][c][py*7+px] = sum_k part[bn][px][k][py][c].
// 512 blocks (bn, 64-ch group); k_final's proven padded-LDS transpose.
__global__ __launch_bounds__(256) void k_reduce(const float* __restrict__ part,
                                                float* __restrict__ out) {
    __shared__ float t[49 * 65];
    int bid = blockIdx.x;                    // bn*4 + cg
    int cg  = bid & 3;
    int bn  = bid >> 2;
    int tid = (int)threadIdx.x;
    const float* pb = part + (size_t)bn * (7 * 9 * 7 * 256) + cg * 64;
    for (int e = tid; e < 49 * 64; e += 256) {
        int q = e >> 6, cl = e & 63;
        int py = q / 7, px = q - py * 7;
        const float* p0 = pb + ((size_t)(px * 63 + py)) * 256 + cl;
        float sum = 0.0f;
#pragma unroll
        for (int k = 0; k < 9; ++k) sum += p0[(size_t)k * (7 * 256)];
        t[q * 65 + cl] = sum;
    }
    __syncthreads();
    float* dst = out + (size_t)bn * (C_ * 49) + (size_t)cg * 64 * 49;
    for (int e = tid; e < 64 * 49; e += 256) {
        int cl = e / 49, q = e - cl * 49;
        dst[e] = t[q * 65 + cl];
    }
}

// ---------------------------------------------------------------------------
// FALLBACK PATH (ws too small): R4-verbatim k_main + k_final (proven 149.4).
__global__ __launch_bounds__(256, 4) void k_main(const float* __restrict__ ws_f,
                                                 const float* __restrict__ boxes,
                                                 const float* __restrict__ gt,
                                                 float* __restrict__ outs) {
    __shared__ float        s_wyf[H_][WROW_];
    __shared__ unsigned int s_wy2[Y2_ * WROW_];
    __shared__ float        s_ax[W_][WROW_];

    int bid = blockIdx.x;
    int j   = bid % JPN_;
    int n   = (bid / JPN_) & (N_ - 1);
    int b   = bid / (JPN_ * N_);
    int k, s;
    if (j == 0) { k = 0; s = 0; }
    else        { k = 1 + ((j - 1) >> 2); s = (j - 1) & 3; }
    int tid = (int)threadIdx.x;
    int c   = tid;

    float bx1, by1, rw, rh;
    gen_weights(k, b, n, tid, boxes, gt, s_wyf, s_wy2, s_ax, bx1, by1, rw, rh);

    int xlo = min(max((int)floorf(fmaxf(bx1, 0.0f)), 0), W_ - 1);
    int xhi = min(max((int)floorf(bx1 + rw) + 1, 0), W_ - 1) + 1;
    int ylo = min(max((int)floorf(fmaxf(by1, 0.0f)), 0), H_ - 1);
    int yhi = min(max((int)floorf(by1 + rh) + 1, 0), H_ - 1) + 1;
    int xs, xe;
    if (k == 0) { xs = xlo; xe = xhi; }
    else {
        int cw = (xhi - xlo + SCTX_ - 1) >> 2;
        xs = xlo + s * cw;
        xe = min(xs + cw, xhi);
    }
    if (xs >= xe) return;

    int ylo4 = ylo >> 2;
    int yhi4 = (yhi + 3) >> 2;

    const uint2* f4 = (const uint2*)ws_f + (size_t)b * (Y4_ * W_ * C_);

    float acc[49];
#pragma unroll
    for (int q = 0; q < 49; ++q) acc[q] = 0.0f;
    int live = 0;

    for (int x = xs; x < xe; x += 4) {
        float cs[4][P_];
#pragma unroll
        for (int i = 0; i < 4; ++i)
#pragma unroll
            for (int py = 0; py < P_; ++py) cs[i][py] = 0.0f;

        const uint2* cp = f4 + ((size_t)(ylo4 * W_ + x)) * C_ + c;

        uint2 d0 = cp[0];
        uint2 d1 = cp[C_];
        uint2 d2 = cp[2 * C_];
        uint2 d3 = cp[3 * C_];
        for (int y4 = ylo4; y4 < yhi4; ++y4) {
            size_t nstep = (y4 + 1 < yhi4) ? (size_t)(W_ * C_) : 0;
            const uint2* cq = cp + nstep;
            uint2 e0 = cq[0];
            uint2 e1 = cq[C_];
            uint2 e2 = cq[2 * C_];
            uint2 e3 = cq[3 * C_];

            uint4 wa0 = *(const uint4*)&s_wy2[(2 * y4) * WROW_];
            uint4 wb0 = *(const uint4*)&s_wy2[(2 * y4) * WROW_ + 4];
            uint4 wa1 = *(const uint4*)&s_wy2[(2 * y4 + 1) * WROW_];
            uint4 wb1 = *(const uint4*)&s_wy2[(2 * y4 + 1) * WROW_ + 4];
            half2v w0[7], w1[7];
            w0[0] = __builtin_bit_cast(half2v, wa0.x);
            w0[1] = __builtin_bit_cast(half2v, wa0.y);
            w0[2] = __builtin_bit_cast(half2v, wa0.z);
            w0[3] = __builtin_bit_cast(half2v, wa0.w);
            w0[4] = __builtin_bit_cast(half2v, wb0.x);
            w0[5] = __builtin_bit_cast(half2v, wb0.y);
            w0[6] = __builtin_bit_cast(half2v, wb0.z);
            w1[0] = __builtin_bit_cast(half2v, wa1.x);
            w1[1] = __builtin_bit_cast(half2v, wa1.y);
            w1[2] = __builtin_bit_cast(half2v, wa1.z);
            w1[3] = __builtin_bit_cast(half2v, wa1.w);
            w1[4] = __builtin_bit_cast(half2v, wb1.x);
            w1[5] = __builtin_bit_cast(half2v, wb1.y);
            w1[6] = __builtin_bit_cast(half2v, wb1.z);
            half2v v0a = __builtin_bit_cast(half2v, d0.x);
            half2v v0b = __builtin_bit_cast(half2v, d0.y);
            half2v v1a = __builtin_bit_cast(half2v, d1.x);
            half2v v1b = __builtin_bit_cast(half2v, d1.y);
            half2v v2a = __builtin_bit_cast(half2v, d2.x);
            half2v v2b = __builtin_bit_cast(half2v, d2.y);
            half2v v3a = __builtin_bit_cast(half2v, d3.x);
            half2v v3b = __builtin_bit_cast(half2v, d3.y);
#pragma unroll
            for (int py = 0; py < P_; ++py) {
                cs[0][py] = FDOT2(w1[py], v0b, FDOT2(w0[py], v0a, cs[0][py]));
                cs[1][py] = FDOT2(w1[py], v1b, FDOT2(w0[py], v1a, cs[1][py]));
                cs[2][py] = FDOT2(w1[py], v2b, FDOT2(w0[py], v2a, cs[2][py]));
                cs[3][py] = FDOT2(w1[py], v3b, FDOT2(w0[py], v3a, cs[3][py]));
            }
            d0 = e0; d1 = e1; d2 = e2; d3 = e3;
            cp = cq;
        }

#pragma unroll
        for (int i = 0; i < 4; ++i) {
            if (x + i < xe) {
                float av[8];
                *(float4*)(&av[0]) = *(const float4*)&s_ax[x + i][0];
                *(float4*)(&av[4]) = *(const float4*)&s_ax[x + i][4];
#pragma unroll
                for (int px = 0; px < P_; ++px) {
                    float w = av[px];
                    if (w != 0.0f) {
                        live |= 1 << px;
#pragma unroll
                        for (int py = 0; py < P_; ++py)
                            acc[py * P_ + px] = fmaf(w, cs[i][py], acc[py * P_ + px]);
                    }
                }
            }
        }
    }

    float* os = outs + ((size_t)b * N_ + n) * (49 * C_) + c;
#pragma unroll
    for (int px = 0; px < P_; ++px) {
        if (live & (1 << px)) {
#pragma unroll
            for (int py = 0; py < P_; ++py)
                atomicAdd(os + (py * P_ + px) * C_, acc[py * P_ + px]);
        }
    }
}

__global__ __launch_bounds__(256) void k_final(const float* __restrict__ outs,
                                               float* __restrict__ out) {
    __shared__ float t[49 * 65];
    int bid = blockIdx.x;
    int cg  = bid & 3;
    int bn  = bid >> 2;
    int tid = (int)threadIdx.x;
    const float* src = outs + (size_t)bn * (49 * C_) + cg * 64;
    for (int e = tid; e < 49 * 64; e += 256) {
        int q = e >> 6, c = e & 63;
        t[q * 65 + c] = src[q * C_ + c];
    }
    __syncthreads();
    float* dst = out + (size_t)bn * (C_ * 49) + (size_t)cg * 64 * 49;
    for (int e = tid; e < 64 * 49; e += 256) {
        int c = e / 49, q = e - c * 49;
        dst[e] = t[q * 65 + c];
    }
}

// ---------------------------------------------------------------------------
extern "C" void kernel_launch(void* const* d_in, const int* in_sizes, int n_in,
                              void* d_out, int out_size, void* d_ws, size_t ws_size,
                              hipStream_t stream) {
    const float* fm    = (const float*)d_in[0];
    const float* boxes = (const float*)d_in[1];
    const float* gt    = (const float*)d_in[2];
    float* ws_f = (float*)d_ws;
    float* out  = (float*)d_out;

    if (ws_size >= WS_BYTES_P) {
        // ---- path P: atomic-free (plain-store partials + reduce) ----
        float* part = ws_f + F_PART;
        k_prep<<<PREP_T, 256, 0, stream>>>(fm, ws_f);
        k_mainP<<<B_ * N_ * JP2_, 256, 0, stream>>>(ws_f, boxes, gt, part);
        k_reduce<<<B_ * N_ * 4, 256, 0, stream>>>(part, out);
    } else {
        // ---- fallback: R4-verbatim proven pipeline ----
        float* outs = ws_f + F_OUTS;
        k_prep<<<PREP_N, 256, 0, stream>>>(fm, ws_f);
        k_main<<<B_ * N_ * JPN_, 256, 0, stream>>>(ws_f, boxes, gt, outs);
        k_final<<<B_ * N_ * 4, 256, 0, stream>>>(outs, out);
    }
}